// Round 1
// 122.095 us; speedup vs baseline: 1.0396x; 1.0396x over previous
//
#include <hip/hip_runtime.h>
#include <math.h>

// Problem constants
#define BATCH 2
#define NTOK  2048
#define FIN   256
#define HEADS 8
#define FOUT  32
#define BH    (BATCH*HEADS)    // 16
#define NCOL  (HEADS*FOUT)     // 256
#define ROWS  (BATCH*NTOK)     // 4096

// ---------------------------------------------------------------------------
// Workspace layout (float offsets) — unchanged; partial ranks alias V1
// (rank8 writes partial -> scatter reads it -> vscan overwrites V1 later;
//  strict stream order makes the aliasing safe).
// V1/P2V are now fg-plane-major: [bh][fg][2049][4] (same total size).
// ---------------------------------------------------------------------------
static const size_t OFF_E1   = 1048576;                 // e1  [16][2048]
static const size_t OFF_E2   = OFF_E1 + 32768;          // e2  [16][2048]
static const size_t OFF_SKEY = OFF_E2 + 32768;          // skey[16][2048]
static const size_t OFF_SIDX = OFF_SKEY + 32768;        // sidx[16][2048] int
static const size_t OFF_W1S  = OFF_SIDX + 32768;        // w1s [16][2048]
static const size_t OFF_W2S  = OFF_W1S + 32768;         // w2s [16][2048]
static const size_t OFF_S1   = OFF_W2S + 32768;         // S1  [16][2049]
static const size_t OFF_P2   = OFF_S1 + 32784;          // P2  [16][2049]
static const size_t OFF_V1   = OFF_P2 + 32784;          // V1  [16][8][2049][4]
static const size_t OFF_P2V  = OFF_V1 + 16u*2049u*32u;  // P2V [16][8][2049][4]
static const size_t OFF_PART = OFF_V1;                  // partial[8][16][2048] int (aliases V1)

// ---------------------------------------------------------------------------
// K1: Wh = h @ W  (4096x256 @ 256x256 fp32).
// Tile 64 rows x 64 cols, BK=32, 256 threads, micro-tile 4x4 -> 2 B/FMA LDS.
// A staged TRANSPOSED (As[k][row]) so the per-k A read is a 4-address
// 16-way-broadcast ds_read_b128 (free); B read is 2-deep (free).
// Double-buffered, ONE barrier per K-step (stores go to the other buffer,
// which no wave can still be reading past the previous barrier).
// grid (64,4)=256 blocks (1/CU), VALU-bound ~4 FMA-cycles per LDS-cycle.
// ---------------------------------------------------------------------------
__global__ __launch_bounds__(256) void k_gemm(const float* __restrict__ h,
                                              const float* __restrict__ W,
                                              float* __restrict__ Wh) {
    __shared__ alignas(16) float As[2][32][68];   // [buf][k][row], stride 68 (16B-aligned rows)
    __shared__ alignas(16) float Bs[2][32][72];   // [buf][k][col], stride 72 (16B-aligned, 2-deep banks)
    const int tid  = threadIdx.x;
    const int row0 = blockIdx.x * 64;
    const int col0 = blockIdx.y * 64;
    const int tx   = tid & 15;      // col quad 0..15
    const int ty   = tid >> 4;      // row quad 0..15
    const int ar   = tid >> 3;      // A stage: row 0..31 (q adds 32)
    const int akq  = tid & 7;       // A stage: k-float4 0..7
    const int bkr  = tid >> 4;      // B stage: k 0..15 (q adds 16)
    const int bcf  = tid & 15;      // B stage: col-float4 0..15
    const int colf = col0 >> 2;

    const float4* __restrict__ h4 = (const float4*)h;   // [4096][64]
    const float4* __restrict__ W4 = (const float4*)W;   // [256][64]

    // prologue: load tile 0 into regs
    float4 a0 = h4[(size_t)(row0 + ar)      * 64 + akq];
    float4 a1 = h4[(size_t)(row0 + 32 + ar) * 64 + akq];
    float4 b0 = W4[(size_t)(bkr)      * 64 + colf + bcf];
    float4 b1 = W4[(size_t)(16 + bkr) * 64 + colf + bcf];

    float4 acc0 = make_float4(0.f,0.f,0.f,0.f);
    float4 acc1 = make_float4(0.f,0.f,0.f,0.f);
    float4 acc2 = make_float4(0.f,0.f,0.f,0.f);
    float4 acc3 = make_float4(0.f,0.f,0.f,0.f);

    for (int t = 0; t < FIN / 32; ++t) {
        const int cur = t & 1;
        // store staged regs -> LDS[cur] (transposing A)
        As[cur][akq*4+0][ar]      = a0.x;
        As[cur][akq*4+1][ar]      = a0.y;
        As[cur][akq*4+2][ar]      = a0.z;
        As[cur][akq*4+3][ar]      = a0.w;
        As[cur][akq*4+0][32 + ar] = a1.x;
        As[cur][akq*4+1][32 + ar] = a1.y;
        As[cur][akq*4+2][32 + ar] = a1.z;
        As[cur][akq*4+3][32 + ar] = a1.w;
        *(float4*)&Bs[cur][bkr][bcf*4]      = b0;
        *(float4*)&Bs[cur][16 + bkr][bcf*4] = b1;
        __syncthreads();
        // prefetch next tile (overlaps the MAC loop below)
        if (t + 1 < FIN / 32) {
            const int kc = (t + 1) * 32;
            a0 = h4[(size_t)(row0 + ar)      * 64 + (kc >> 2) + akq];
            a1 = h4[(size_t)(row0 + 32 + ar) * 64 + (kc >> 2) + akq];
            b0 = W4[(size_t)(kc + bkr)      * 64 + colf + bcf];
            b1 = W4[(size_t)(kc + 16 + bkr) * 64 + colf + bcf];
        }
        #pragma unroll
        for (int k = 0; k < 32; ++k) {
            float4 a4 = *(const float4*)&As[cur][k][ty*4];   // rows ty*4..+3 @ k (broadcast)
            float4 b4 = *(const float4*)&Bs[cur][k][tx*4];   // cols tx*4..+3 @ k
            acc0.x += a4.x*b4.x; acc0.y += a4.x*b4.y; acc0.z += a4.x*b4.z; acc0.w += a4.x*b4.w;
            acc1.x += a4.y*b4.x; acc1.y += a4.y*b4.y; acc1.z += a4.y*b4.z; acc1.w += a4.y*b4.w;
            acc2.x += a4.z*b4.x; acc2.y += a4.z*b4.y; acc2.z += a4.z*b4.z; acc2.w += a4.z*b4.w;
            acc3.x += a4.w*b4.x; acc3.y += a4.w*b4.y; acc3.z += a4.w*b4.z; acc3.w += a4.w*b4.w;
        }
        // no second barrier: next iter stores to the OTHER buffer, which every
        // wave finished reading before the barrier above.
    }
    const int orow = row0 + ty*4;
    *(float4*)(Wh + (size_t)(orow + 0) * NCOL + col0 + tx*4) = acc0;
    *(float4*)(Wh + (size_t)(orow + 1) * NCOL + col0 + tx*4) = acc1;
    *(float4*)(Wh + (size_t)(orow + 2) * NCOL + col0 + tx*4) = acc2;
    *(float4*)(Wh + (size_t)(orow + 3) * NCOL + col0 + tx*4) = acc3;
}

// ---------------------------------------------------------------------------
// K2: e1[bh][n] = dot(Wh[b,n,h,:], a1), e2 likewise with a2
// ---------------------------------------------------------------------------
__global__ __launch_bounds__(256) void k_e12(const float* __restrict__ Wh,
                                             const float* __restrict__ a,
                                             float* __restrict__ e1,
                                             float* __restrict__ e2) {
    __shared__ float av[64];
    const int tid = threadIdx.x;
    if (tid < 64) av[tid] = a[tid];
    __syncthreads();

    const int g     = blockIdx.x * 256 + tid;   // 0..32767
    const int n_lin = g >> 3;
    const int hh    = g & 7;
    const float4* p = (const float4*)(Wh + (size_t)n_lin * NCOL + hh * FOUT);
    float s1 = 0.f, s2 = 0.f;
    #pragma unroll
    for (int q = 0; q < 8; ++q) {
        float4 v = p[q];
        s1 += v.x * av[q*4+0] + v.y * av[q*4+1] + v.z * av[q*4+2] + v.w * av[q*4+3];
        s2 += v.x * av[32+q*4+0] + v.y * av[32+q*4+1] + v.z * av[32+q*4+2] + v.w * av[32+q*4+3];
    }
    const int b  = n_lin >> 11;
    const int n  = n_lin & (NTOK - 1);
    const int bh = b * HEADS + hh;
    e1[bh * NTOK + n] = s1;
    e2[bh * NTOK + n] = s2;
}

// ---------------------------------------------------------------------------
// Monotone float->u32 bit map packed with (2047-j): one u64 compare replaces
// the 3-comparison descending-with-index-tiebreak predicate (identical total
// order: u_k > u_j, or equal and k < j).
// ---------------------------------------------------------------------------
__device__ __forceinline__ unsigned long long sortkey(float f, int j) {
    unsigned int b = __float_as_uint(f);
    unsigned int u = (b & 0x80000000u) ? ~b : (b | 0x80000000u);
    return ((unsigned long long)u << 32) | (unsigned int)(NTOK - 1 - j);
}

// ---------------------------------------------------------------------------
// K3a: partial descending ranks. grid (16 bh, 8 jtile, 8 ktile), block 256.
// u64 packed keys: rank loop is cmp_gt_u64 + add (2 VALU/elem vs ~6).
// ---------------------------------------------------------------------------
__global__ __launch_bounds__(256) void k_rank8(const float* __restrict__ e2g,
                                               int* __restrict__ partial) {
    __shared__ alignas(16) unsigned long long ch[256];
    const int tid = threadIdx.x;
    const int bh  = blockIdx.x;
    const int jt  = blockIdx.y;
    const int kt  = blockIdx.z;
    const int kbase = kt * 256;
    ch[tid] = sortkey(e2g[bh * NTOK + kbase + tid], kbase + tid);
    __syncthreads();

    const int j = jt * 256 + tid;
    const unsigned long long my = sortkey(e2g[bh * NTOK + j], j);
    int rank = 0;
    const ulonglong2* c2 = (const ulonglong2*)ch;
    #pragma unroll 8
    for (int q = 0; q < 128; ++q) {
        ulonglong2 v = c2[q];
        rank += (v.x > my);
        rank += (v.y > my);
    }
    partial[(kt * BH + bh) * NTOK + j] = rank;
}

// ---------------------------------------------------------------------------
// K3b: sum 8 partials -> rank; scatter key/idx and exp weights.
// grid (16,8), block 256.
// ---------------------------------------------------------------------------
__global__ __launch_bounds__(256) void k_scatter(const float* __restrict__ e2g,
                                                 const int* __restrict__ partial,
                                                 float* __restrict__ skey,
                                                 int* __restrict__ sidx,
                                                 float* __restrict__ w1s,
                                                 float* __restrict__ w2s) {
    const int tid = threadIdx.x;
    const int bh  = blockIdx.x;
    const int jt  = blockIdx.y;
    const int j   = jt * 256 + tid;
    int rank = 0;
    #pragma unroll
    for (int kt = 0; kt < 8; ++kt)
        rank += partial[(kt * BH + bh) * NTOK + j];
    const float my = e2g[bh * NTOK + j];
    skey[bh * NTOK + rank] = my;
    sidx[bh * NTOK + rank] = j;
    w1s[bh * NTOK + rank]  = expf(my);
    w2s[bh * NTOK + rank]  = expf(0.01f * my);
}

// ---------------------------------------------------------------------------
// K4: work-efficient scans. grid (9 fg, 16 bh, 2 z), block 1024.
// fg<8 : float4 scan of w*Wh[.., fg*4..]  -> V1 (z=0) / P2V (z=1)
// fg==8: scalar scan of w                 -> S1 (z=0) / P2  (z=1)
// V1/P2V are fg-plane-major [bh][fg][2049][4]: each thread writes 32B
// contiguous, each wave 2KB contiguous (was 16B @ 256B stride).
// ---------------------------------------------------------------------------
__global__ __launch_bounds__(1024) void k_vscan(const float* __restrict__ Wh,
                                                const int* __restrict__ sidx,
                                                const float* __restrict__ w1s,
                                                const float* __restrict__ w2s,
                                                float* __restrict__ V1,
                                                float* __restrict__ P2V,
                                                float* __restrict__ S1,
                                                float* __restrict__ P2) {
    __shared__ float4 wtot[16];
    __shared__ float4 woff[16];
    const int t    = threadIdx.x;
    const int lane = t & 63;
    const int wv   = t >> 6;
    const int fg   = blockIdx.x;
    const int bh   = blockIdx.y;
    const int z    = blockIdx.z;
    const int b    = bh >> 3;
    const int hh   = bh & 7;
    const float* wsrc = z ? w2s : w1s;

    const int j0 = 2 * t;
    float4 v0, v1;
    if (fg < 8) {
        int sj0 = sidx[bh * NTOK + j0];
        int sj1 = sidx[bh * NTOK + j0 + 1];
        float w0 = wsrc[bh * NTOK + j0];
        float w1 = wsrc[bh * NTOK + j0 + 1];
        float4 g0 = *(const float4*)(Wh + (size_t)(b * NTOK + sj0) * NCOL + hh * FOUT + fg * 4);
        float4 g1 = *(const float4*)(Wh + (size_t)(b * NTOK + sj1) * NCOL + hh * FOUT + fg * 4);
        v0 = make_float4(w0 * g0.x, w0 * g0.y, w0 * g0.z, w0 * g0.w);
        v1 = make_float4(w1 * g1.x, w1 * g1.y, w1 * g1.z, w1 * g1.w);
    } else {
        v0 = make_float4(wsrc[bh * NTOK + j0],     0.f, 0.f, 0.f);
        v1 = make_float4(wsrc[bh * NTOK + j0 + 1], 0.f, 0.f, 0.f);
    }

    // thread-local pair sum, then inclusive wave scan
    float4 s = make_float4(v0.x + v1.x, v0.y + v1.y, v0.z + v1.z, v0.w + v1.w);
    #pragma unroll
    for (int d = 1; d < 64; d <<= 1) {
        float ux = __shfl_up(s.x, (unsigned)d, 64);
        float uy = __shfl_up(s.y, (unsigned)d, 64);
        float uz = __shfl_up(s.z, (unsigned)d, 64);
        float uw = __shfl_up(s.w, (unsigned)d, 64);
        if (lane >= d) { s.x += ux; s.y += uy; s.z += uz; s.w += uw; }
    }
    // exclusive-within-wave
    float4 pair = make_float4(v0.x + v1.x, v0.y + v1.y, v0.z + v1.z, v0.w + v1.w);
    float4 excl = make_float4(s.x - pair.x, s.y - pair.y, s.z - pair.z, s.w - pair.w);
    if (lane == 63) wtot[wv] = s;
    __syncthreads();
    if (t < 16) {
        float4 ws = wtot[t];
        float4 inc = ws;
        #pragma unroll
        for (int d = 1; d < 16; d <<= 1) {
            float ux = __shfl_up(inc.x, (unsigned)d, 16);
            float uy = __shfl_up(inc.y, (unsigned)d, 16);
            float uz = __shfl_up(inc.z, (unsigned)d, 16);
            float uw = __shfl_up(inc.w, (unsigned)d, 16);
            if ((t & 15) >= d) { inc.x += ux; inc.y += uy; inc.z += uz; inc.w += uw; }
        }
        woff[t] = make_float4(inc.x - ws.x, inc.y - ws.y, inc.z - ws.z, inc.w - ws.w);
    }
    __syncthreads();

    float4 base = woff[wv];
    float4 i0 = make_float4(base.x + excl.x + v0.x, base.y + excl.y + v0.y,
                            base.z + excl.z + v0.z, base.w + excl.w + v0.w);
    float4 i1 = make_float4(i0.x + v1.x, i0.y + v1.y, i0.z + v1.z, i0.w + v1.w);

    if (fg < 8) {
        float* dst = z ? P2V : V1;
        float* plane = dst + ((size_t)bh * 8 + fg) * (2049u * 4u);
        *(float4*)(plane + (size_t)(j0 + 1) * 4) = i0;
        *(float4*)(plane + (size_t)(j0 + 2) * 4) = i1;
        if (t == 0)
            *(float4*)plane = make_float4(0.f,0.f,0.f,0.f);
    } else {
        float* dst = z ? P2 : S1;
        dst[bh * 2049 + j0 + 1] = i0.x;
        dst[bh * 2049 + j0 + 2] = i1.x;
        if (t == 0) dst[bh * 2049] = 0.f;
    }
}

// ---------------------------------------------------------------------------
// K5: per (b,h,i): binary-search k_i, combine prefix sums, write output.
// grid (64 itile, 16 bh), block 256 = 32 i x 8 fg
// ---------------------------------------------------------------------------
__global__ __launch_bounds__(256) void k_out(const float* __restrict__ skey,
                                             const float* __restrict__ e1g,
                                             const float* __restrict__ S1,
                                             const float* __restrict__ P2,
                                             const float* __restrict__ V1,
                                             const float* __restrict__ P2V,
                                             float* __restrict__ out) {
    __shared__ float keys[NTOK];
    const int tid = threadIdx.x;
    const int it  = blockIdx.x;
    const int bh  = blockIdx.y;
    const int b   = bh >> 3;
    const int hh  = bh & 7;
    #pragma unroll
    for (int q = 0; q < 8; ++q)
        keys[q * 256 + tid] = skey[bh * NTOK + q * 256 + tid];
    __syncthreads();

    const int i  = it * 32 + (tid >> 3);
    const int fg = tid & 7;
    const float e1v = e1g[bh * NTOK + i];
    const float th  = -e1v;
    int lo = 0, hi = NTOK;
    while (lo < hi) {
        int mid = (lo + hi) >> 1;
        if (keys[mid] > th) lo = mid + 1; else hi = mid;
    }
    const int k = lo;
    const float A = expf(e1v);
    const float C = expf(0.01f * e1v);
    const float s1  = S1[bh * 2049 + k];
    const float p2k = P2[bh * 2049 + k];
    const float p2t = P2[bh * 2049 + 2048];
    const float l   = A * s1 + C * (p2t - p2k);
    const float inv = 1.0f / l;
    const float* v1p  = V1  + ((size_t)bh * 8 + fg) * (2049u * 4u);
    const float* p2vp = P2V + ((size_t)bh * 8 + fg) * (2049u * 4u);
    float4 v1   = *(const float4*)(v1p  + (size_t)k * 4);
    float4 p2v  = *(const float4*)(p2vp + (size_t)k * 4);
    float4 p2vt = *(const float4*)(p2vp + (size_t)2048 * 4);
    float4 o;
    o.x = (A * v1.x + C * (p2vt.x - p2v.x)) * inv;
    o.y = (A * v1.y + C * (p2vt.y - p2v.y)) * inv;
    o.z = (A * v1.z + C * (p2vt.z - p2v.z)) * inv;
    o.w = (A * v1.w + C * (p2vt.w - p2v.w)) * inv;
    *(float4*)(out + (size_t)(b * NTOK + i) * NCOL + hh * FOUT + fg * 4) = o;
}

// ---------------------------------------------------------------------------
extern "C" void kernel_launch(void* const* d_in, const int* in_sizes, int n_in,
                              void* d_out, int out_size, void* d_ws, size_t ws_size,
                              hipStream_t stream) {
    const float* h = (const float*)d_in[0];
    // d_in[1] = adj — unused by the reference computation
    const float* W = (const float*)d_in[2];
    const float* a = (const float*)d_in[3];
    float* out = (float*)d_out;
    float* ws  = (float*)d_ws;

    float* Wh   = ws;
    float* e1   = ws + OFF_E1;
    float* e2   = ws + OFF_E2;
    float* skey = ws + OFF_SKEY;
    int*   sidx = (int*)(ws + OFF_SIDX);
    float* w1s  = ws + OFF_W1S;
    float* w2s  = ws + OFF_W2S;
    float* S1   = ws + OFF_S1;
    float* P2   = ws + OFF_P2;
    float* V1   = ws + OFF_V1;
    float* P2V  = ws + OFF_P2V;
    int*   part = (int*)(ws + OFF_PART);   // aliases V1 (safe: consumed before vscan)

    k_gemm   <<<dim3(ROWS / 64, NCOL / 64), 256, 0, stream>>>(h, W, Wh);
    k_e12    <<<dim3(ROWS * HEADS / 256),   256, 0, stream>>>(Wh, a, e1, e2);
    k_rank8  <<<dim3(BH, 8, 8),             256, 0, stream>>>(e2, part);
    k_scatter<<<dim3(BH, 8),                256, 0, stream>>>(e2, part, skey, sidx, w1s, w2s);
    k_vscan  <<<dim3(9, BH, 2),            1024, 0, stream>>>(Wh, sidx, w1s, w2s, V1, P2V, S1, P2);
    k_out    <<<dim3(NTOK / 32, BH),        256, 0, stream>>>(skey, e1, S1, P2, V1, P2V, out);
}